// Round 1
// baseline (33869.055 us; speedup 1.0000x reference)
//
#include <hip/hip_runtime.h>
#include <math.h>

#define SEQ   16384
#define DIM   1024
#define WU    96                    // warm-up steps per chunk
#define CHUNK 32                    // output steps per chunk
#define NCH   (SEQ / CHUNK)         // 512 chunks per direction
#define NSTR  (2 * NCH)             // 1024 parallel streams (fwd+bwd)
#define NSTEP (WU + CHUNK)          // 128 batched steps

// ---------------------------------------------------------------------------
// xproj = x @ Wx + b   (16384 x 1024) = (16384 x 1024)(1024 x 1024)
// 64x64 block tile, 256 threads, 4x4 per-thread tile.
// A staged transposed in LDS (stride 66 -> 4-way-max write conflicts, b64
// aligned reads); B streamed straight from global (L2-resident, row-band-major
// block order keeps the x panel hot in L2).
// ---------------------------------------------------------------------------
__global__ __launch_bounds__(256)
void xproj_kernel(const float* __restrict__ x, const float* __restrict__ Wx,
                  const float* __restrict__ b, float* __restrict__ xp)
{
    const int bid  = blockIdx.x;
    const int bcol = bid & 15;            // 16 col tiles (inner -> row band stays in L2)
    const int brow = bid >> 4;            // 256 row tiles
    const int row0 = brow * 64, col0 = bcol * 64;
    const int tid = threadIdx.x;
    const int q = tid & 15;               // rows 4q..4q+3
    const int p = tid >> 4;               // cols 4p..4p+3
    __shared__ float At[64][66];          // At[k][row]

    float acc[4][4] = {};
    for (int k0 = 0; k0 < DIM; k0 += 64) {
#pragma unroll
        for (int it = 0; it < 4; ++it) {
            int f  = tid + 256 * it;      // 0..1023 float4 units
            int r  = f >> 4;              // 0..63
            int k4 = (f & 15) << 2;       // 0..60
            const float4 v = *reinterpret_cast<const float4*>(
                &x[(size_t)(row0 + r) * DIM + k0 + k4]);
            At[k4 + 0][r] = v.x; At[k4 + 1][r] = v.y;
            At[k4 + 2][r] = v.z; At[k4 + 3][r] = v.w;
        }
        __syncthreads();
#pragma unroll 4
        for (int k = 0; k < 64; ++k) {
            const float2 a01 = *reinterpret_cast<const float2*>(&At[k][4 * q]);
            const float2 a23 = *reinterpret_cast<const float2*>(&At[k][4 * q + 2]);
            const float4 b4  = *reinterpret_cast<const float4*>(
                &Wx[(size_t)(k0 + k) * DIM + col0 + 4 * p]);
            const float a0 = a01.x, a1 = a01.y, a2 = a23.x, a3 = a23.y;
            acc[0][0] += a0 * b4.x; acc[0][1] += a0 * b4.y; acc[0][2] += a0 * b4.z; acc[0][3] += a0 * b4.w;
            acc[1][0] += a1 * b4.x; acc[1][1] += a1 * b4.y; acc[1][2] += a1 * b4.z; acc[1][3] += a1 * b4.w;
            acc[2][0] += a2 * b4.x; acc[2][1] += a2 * b4.y; acc[2][2] += a2 * b4.z; acc[2][3] += a2 * b4.w;
            acc[3][0] += a3 * b4.x; acc[3][1] += a3 * b4.y; acc[3][2] += a3 * b4.z; acc[3][3] += a3 * b4.w;
        }
        __syncthreads();
    }
    const float4 bb = *reinterpret_cast<const float4*>(&b[col0 + 4 * p]);
#pragma unroll
    for (int e = 0; e < 4; ++e) {
        float4 z;
        z.x = acc[e][0] + bb.x; z.y = acc[e][1] + bb.y;
        z.z = acc[e][2] + bb.z; z.w = acc[e][3] + bb.w;
        *reinterpret_cast<float4*>(
            &xp[(size_t)(row0 + 4 * q + e) * DIM + col0 + 4 * p]) = z;
    }
}

// ---------------------------------------------------------------------------
// One batched recurrence step over all 1024 streams:
//   Hnew[s][:] = tanh(xp[row(s)][:] + Hold[s][:] @ Wh)         (masked t<0)
// stream s: dir = s>>9, chunk c = s&511, t = c*CHUNK + (i - WU)
//   fwd: xp row t,          out row t
//   bwd: xp row SEQ-1-t,    out row SEQ+t
// Same 64x64 tiling as xproj; grid = 16x16 = 256 blocks (one per CU).
// ---------------------------------------------------------------------------
__global__ __launch_bounds__(256)
void step_kernel(const float* __restrict__ Hold, float* __restrict__ Hnew,
                 const float* __restrict__ xp, const float* __restrict__ Wh,
                 float* __restrict__ out, const int i)
{
    const int bid  = blockIdx.x;
    const int bcol = bid & 15;            // 16 col tiles
    const int brow = bid >> 4;            // 16 row tiles (1024 streams)
    const int row0 = brow * 64, col0 = bcol * 64;
    const int tid = threadIdx.x;
    const int q = tid & 15;
    const int p = tid >> 4;
    __shared__ float At[64][66];

    float acc[4][4] = {};
    for (int k0 = 0; k0 < DIM; k0 += 64) {
#pragma unroll
        for (int it = 0; it < 4; ++it) {
            int f  = tid + 256 * it;
            int r  = f >> 4;
            int k4 = (f & 15) << 2;
            const float4 v = *reinterpret_cast<const float4*>(
                &Hold[(size_t)(row0 + r) * DIM + k0 + k4]);
            At[k4 + 0][r] = v.x; At[k4 + 1][r] = v.y;
            At[k4 + 2][r] = v.z; At[k4 + 3][r] = v.w;
        }
        __syncthreads();
#pragma unroll 4
        for (int k = 0; k < 64; ++k) {
            const float2 a01 = *reinterpret_cast<const float2*>(&At[k][4 * q]);
            const float2 a23 = *reinterpret_cast<const float2*>(&At[k][4 * q + 2]);
            const float4 b4  = *reinterpret_cast<const float4*>(
                &Wh[(size_t)(k0 + k) * DIM + col0 + 4 * p]);
            const float a0 = a01.x, a1 = a01.y, a2 = a23.x, a3 = a23.y;
            acc[0][0] += a0 * b4.x; acc[0][1] += a0 * b4.y; acc[0][2] += a0 * b4.z; acc[0][3] += a0 * b4.w;
            acc[1][0] += a1 * b4.x; acc[1][1] += a1 * b4.y; acc[1][2] += a1 * b4.z; acc[1][3] += a1 * b4.w;
            acc[2][0] += a2 * b4.x; acc[2][1] += a2 * b4.y; acc[2][2] += a2 * b4.z; acc[2][3] += a2 * b4.w;
            acc[3][0] += a3 * b4.x; acc[3][1] += a3 * b4.y; acc[3][2] += a3 * b4.z; acc[3][3] += a3 * b4.w;
        }
        __syncthreads();
    }

#pragma unroll
    for (int e = 0; e < 4; ++e) {
        const int s   = row0 + 4 * q + e;
        const int dir = s >> 9;
        const int c   = s & 511;
        const int t   = c * CHUNK + (i - WU);
        float4 h;
        if (t < 0) {
            h.x = 0.f; h.y = 0.f; h.z = 0.f; h.w = 0.f;   // exact masked warm-up (chunk 0)
        } else {
            const int xrow = dir ? (SEQ - 1 - t) : t;
            const float4 xv = *reinterpret_cast<const float4*>(
                &xp[(size_t)xrow * DIM + col0 + 4 * p]);
            h.x = tanhf(acc[e][0] + xv.x);
            h.y = tanhf(acc[e][1] + xv.y);
            h.z = tanhf(acc[e][2] + xv.z);
            h.w = tanhf(acc[e][3] + xv.w);
        }
        *reinterpret_cast<float4*>(&Hnew[(size_t)s * DIM + col0 + 4 * p]) = h;
        if (i >= WU) {                                     // t >= 0 guaranteed here
            const int orow = dir ? (SEQ + t) : t;
            *reinterpret_cast<float4*>(&out[(size_t)orow * DIM + col0 + 4 * p]) = h;
        }
    }
}

// ---------------------------------------------------------------------------
extern "C" void kernel_launch(void* const* d_in, const int* in_sizes, int n_in,
                              void* d_out, int out_size, void* d_ws, size_t ws_size,
                              hipStream_t stream)
{
    (void)in_sizes; (void)n_in; (void)out_size; (void)ws_size;
    const float* x  = (const float*)d_in[0];
    const float* Wx = (const float*)d_in[1];
    const float* Wh = (const float*)d_in[2];
    const float* b  = (const float*)d_in[3];
    float* out = (float*)d_out;

    char*  ws = (char*)d_ws;
    float* xp = (float*)ws;                                  // 64 MiB
    float* H0 = (float*)(ws + (size_t)SEQ * DIM * sizeof(float));
    float* H1 = H0 + (size_t)NSTR * DIM;                     // 4 MiB each

    hipLaunchKernelGGL(xproj_kernel, dim3(4096), dim3(256), 0, stream, x, Wx, b, xp);
    hipMemsetAsync(H0, 0, (size_t)NSTR * DIM * sizeof(float), stream);

    float* cur = H0;
    float* nxt = H1;
    for (int i = 0; i < NSTEP; ++i) {
        hipLaunchKernelGGL(step_kernel, dim3(256), dim3(256), 0, stream,
                           cur, nxt, xp, Wh, out, i);
        float* tmp = cur; cur = nxt; nxt = tmp;
    }
}

// Round 2
// 2887.468 us; speedup vs baseline: 11.7297x; 11.7297x over previous
//
#include <hip/hip_runtime.h>
#include <math.h>

#define SEQ   16384
#define DIM   1024
#define WU    96                    // warm-up steps per chunk
#define CHUNK 32                    // output steps per chunk
#define NCH   (SEQ / CHUNK)         // 512 chunks per direction
#define NSTR  (2 * NCH)             // 1024 parallel streams (fwd+bwd)
#define NSTEP (WU + CHUNK)          // 128 batched steps

typedef __attribute__((ext_vector_type(8))) short bf16x8;   // 8 bf16 in 4 VGPRs
typedef __attribute__((ext_vector_type(4))) float f32x4;    // MFMA 16x16 accum

// bf16 round-to-nearest-even, bit-level (no hip_bf16 type pitfalls)
__device__ __forceinline__ unsigned short f2bf(float f) {
    unsigned int x = __float_as_uint(f);
    unsigned int r = (x + 0x7fffu + ((x >> 16) & 1u)) >> 16;
    return (unsigned short)r;
}
__device__ __forceinline__ float bf2f(unsigned short u) {
    return __uint_as_float(((unsigned int)u) << 16);
}

// ---------------------------------------------------------------------------
// xproj = x @ Wx + b  (unchanged from round 1; ~760us, optimize next round)
// ---------------------------------------------------------------------------
__global__ __launch_bounds__(256)
void xproj_kernel(const float* __restrict__ x, const float* __restrict__ Wx,
                  const float* __restrict__ b, float* __restrict__ xp)
{
    const int bid  = blockIdx.x;
    const int bcol = bid & 15;
    const int brow = bid >> 4;
    const int row0 = brow * 64, col0 = bcol * 64;
    const int tid = threadIdx.x;
    const int q = tid & 15;
    const int p = tid >> 4;
    __shared__ float At[64][66];

    float acc[4][4] = {};
    for (int k0 = 0; k0 < DIM; k0 += 64) {
#pragma unroll
        for (int it = 0; it < 4; ++it) {
            int f  = tid + 256 * it;
            int r  = f >> 4;
            int k4 = (f & 15) << 2;
            const float4 v = *reinterpret_cast<const float4*>(
                &x[(size_t)(row0 + r) * DIM + k0 + k4]);
            At[k4 + 0][r] = v.x; At[k4 + 1][r] = v.y;
            At[k4 + 2][r] = v.z; At[k4 + 3][r] = v.w;
        }
        __syncthreads();
#pragma unroll 4
        for (int k = 0; k < 64; ++k) {
            const float2 a01 = *reinterpret_cast<const float2*>(&At[k][4 * q]);
            const float2 a23 = *reinterpret_cast<const float2*>(&At[k][4 * q + 2]);
            const float4 b4  = *reinterpret_cast<const float4*>(
                &Wx[(size_t)(k0 + k) * DIM + col0 + 4 * p]);
            const float a0 = a01.x, a1 = a01.y, a2 = a23.x, a3 = a23.y;
            acc[0][0] += a0 * b4.x; acc[0][1] += a0 * b4.y; acc[0][2] += a0 * b4.z; acc[0][3] += a0 * b4.w;
            acc[1][0] += a1 * b4.x; acc[1][1] += a1 * b4.y; acc[1][2] += a1 * b4.z; acc[1][3] += a1 * b4.w;
            acc[2][0] += a2 * b4.x; acc[2][1] += a2 * b4.y; acc[2][2] += a2 * b4.z; acc[2][3] += a2 * b4.w;
            acc[3][0] += a3 * b4.x; acc[3][1] += a3 * b4.y; acc[3][2] += a3 * b4.z; acc[3][3] += a3 * b4.w;
        }
        __syncthreads();
    }
    const float4 bb = *reinterpret_cast<const float4*>(&b[col0 + 4 * p]);
#pragma unroll
    for (int e = 0; e < 4; ++e) {
        float4 z;
        z.x = acc[e][0] + bb.x; z.y = acc[e][1] + bb.y;
        z.z = acc[e][2] + bb.z; z.w = acc[e][3] + bb.w;
        *reinterpret_cast<float4*>(
            &xp[(size_t)(row0 + 4 * q + e) * DIM + col0 + 4 * p]) = z;
    }
}

// ---------------------------------------------------------------------------
// Wh (k-major KxN fp32) -> WhT hi/lo (n-major NxK bf16 pair), once per launch.
// 64x64 LDS-tiled transpose, both global sides coalesced.
// ---------------------------------------------------------------------------
__global__ __launch_bounds__(256)
void whsplit_kernel(const float* __restrict__ Wh,
                    unsigned short* __restrict__ WhTh,
                    unsigned short* __restrict__ WhTl)
{
    const int bk = blockIdx.x & 15, bn = blockIdx.x >> 4;
    const int k0 = bk * 64, n0 = bn * 64;
    const int tid = threadIdx.x;
    __shared__ float T[64][65];
#pragma unroll
    for (int it = 0; it < 4; ++it) {
        int f = tid + 256 * it;           // 1024 float4 units
        int r = f >> 4;                   // k row 0..63
        int c4 = (f & 15) << 2;           // n col
        const float4 v = *reinterpret_cast<const float4*>(
            &Wh[(size_t)(k0 + r) * DIM + n0 + c4]);
        T[r][c4 + 0] = v.x; T[r][c4 + 1] = v.y;
        T[r][c4 + 2] = v.z; T[r][c4 + 3] = v.w;
    }
    __syncthreads();
#pragma unroll
    for (int it = 0; it < 4; ++it) {
        int f  = tid + 256 * it;
        int rn = f >> 4;                  // n row of WhT
        int c4 = (f & 15) << 2;           // k col
        ushort4 hi, lo;
        float vv[4] = {T[c4 + 0][rn], T[c4 + 1][rn], T[c4 + 2][rn], T[c4 + 3][rn]};
        unsigned short h[4], l[4];
#pragma unroll
        for (int j = 0; j < 4; ++j) {
            h[j] = f2bf(vv[j]);
            l[j] = f2bf(vv[j] - bf2f(h[j]));
        }
        hi.x = h[0]; hi.y = h[1]; hi.z = h[2]; hi.w = h[3];
        lo.x = l[0]; lo.y = l[1]; lo.z = l[2]; lo.w = l[3];
        *reinterpret_cast<ushort4*>(&WhTh[(size_t)(n0 + rn) * DIM + k0 + c4]) = hi;
        *reinterpret_cast<ushort4*>(&WhTl[(size_t)(n0 + rn) * DIM + k0 + c4]) = lo;
    }
}

// ---------------------------------------------------------------------------
// One batched recurrence step, MFMA bf16 hi/lo split:
//   S = Hhi*Whhi + Hhi*Whlo + Hlo*Whhi  (fp32 accum, ~fp32-accurate)
//   h = tanh(S + xp[row(s)]);  carry h as bf16 hi/lo; emit fp32 when i>=WU.
// Tile: BM=32 (streams) x BN=64 (hidden), BK=64. Grid 512 = 2 blocks/CU.
// 4 waves 2x2, each wave 16x32 (1 m-frag x 2 n-frags, 16x16x32 MFMA).
// LDS double-buffered, k-contiguous [row][72] (pad -> 2-way conflicts = free).
// ---------------------------------------------------------------------------
#define BM 32
#define BN 64
#define BK 64

__global__ __launch_bounds__(256)
void step_mfma(const unsigned short* __restrict__ Hhi_in,
               const unsigned short* __restrict__ Hlo_in,
               unsigned short* __restrict__ Hhi_out,
               unsigned short* __restrict__ Hlo_out,
               const float* __restrict__ xp,
               const unsigned short* __restrict__ WhTh,
               const unsigned short* __restrict__ WhTl,
               float* __restrict__ out, const int i)
{
    // bijective XCD chunk swizzle (512 = 8*64): each XCD owns 2 bn panels
    int bid = (blockIdx.x & 7) * 64 + (blockIdx.x >> 3);
    const int bm = bid & 31, bn = bid >> 5;
    const int row0 = bm * BM, col0 = bn * BN;
    const int tid  = threadIdx.x;
    const int lane = tid & 63, w = tid >> 6;
    const int wm = w >> 1, wn = w & 1;            // wave tile at (wm*16, wn*32)

    __shared__ unsigned short Ah[2][BM][72], Al[2][BM][72];
    __shared__ unsigned short Bh[2][BN][72], Bl[2][BN][72];

    f32x4 acc0 = {0.f, 0.f, 0.f, 0.f};
    f32x4 acc1 = {0.f, 0.f, 0.f, 0.f};

    // staging: A tile 32x64 = 256 x (8 bf16); B tile 64x64 = 512 chunks
    const int ar  = tid >> 3;                     // 0..31
    const int ak  = (tid & 7) * 8;                // 0..56
    const int br1 = ar + 32;
    const size_t aoff  = (size_t)(row0 + ar) * DIM + ak;
    const size_t boff0 = (size_t)(col0 + ar) * DIM + ak;
    const size_t boff1 = (size_t)(col0 + br1) * DIM + ak;

    uint4 ga_h, ga_l, gb_h0, gb_l0, gb_h1, gb_l1;

#define LOADR(kk) do {                                                        \
        ga_h  = *reinterpret_cast<const uint4*>(Hhi_in + aoff  + (kk));       \
        ga_l  = *reinterpret_cast<const uint4*>(Hlo_in + aoff  + (kk));       \
        gb_h0 = *reinterpret_cast<const uint4*>(WhTh   + boff0 + (kk));       \
        gb_h1 = *reinterpret_cast<const uint4*>(WhTh   + boff1 + (kk));       \
        gb_l0 = *reinterpret_cast<const uint4*>(WhTl   + boff0 + (kk));       \
        gb_l1 = *reinterpret_cast<const uint4*>(WhTl   + boff1 + (kk));       \
    } while (0)

#define WRITES(buf) do {                                                      \
        *reinterpret_cast<uint4*>(&Ah[buf][ar][ak])  = ga_h;                  \
        *reinterpret_cast<uint4*>(&Al[buf][ar][ak])  = ga_l;                  \
        *reinterpret_cast<uint4*>(&Bh[buf][ar][ak])  = gb_h0;                 \
        *reinterpret_cast<uint4*>(&Bh[buf][br1][ak]) = gb_h1;                 \
        *reinterpret_cast<uint4*>(&Bl[buf][ar][ak])  = gb_l0;                 \
        *reinterpret_cast<uint4*>(&Bl[buf][br1][ak]) = gb_l1;                 \
    } while (0)

    LOADR(0);
    WRITES(0);
    __syncthreads();
    int cur = 0;

    const int arow = wm * 16 + (lane & 15);
    const int k8   = (lane >> 4) * 8;
    const int bc0  = wn * 32 + (lane & 15);
    const int bc1  = bc0 + 16;

    for (int ks = 0; ks < 16; ++ks) {
        if (ks < 15) LOADR((size_t)(ks + 1) * BK);
#pragma unroll
        for (int kf = 0; kf < 2; ++kf) {
            const int ko = kf * 32 + k8;
            bf16x8 a_h  = *reinterpret_cast<const bf16x8*>(&Ah[cur][arow][ko]);
            bf16x8 a_l  = *reinterpret_cast<const bf16x8*>(&Al[cur][arow][ko]);
            bf16x8 b_h0 = *reinterpret_cast<const bf16x8*>(&Bh[cur][bc0][ko]);
            bf16x8 b_h1 = *reinterpret_cast<const bf16x8*>(&Bh[cur][bc1][ko]);
            bf16x8 b_l0 = *reinterpret_cast<const bf16x8*>(&Bl[cur][bc0][ko]);
            bf16x8 b_l1 = *reinterpret_cast<const bf16x8*>(&Bl[cur][bc1][ko]);
            acc0 = __builtin_amdgcn_mfma_f32_16x16x32_bf16(a_h, b_h0, acc0, 0, 0, 0);
            acc1 = __builtin_amdgcn_mfma_f32_16x16x32_bf16(a_h, b_h1, acc1, 0, 0, 0);
            acc0 = __builtin_amdgcn_mfma_f32_16x16x32_bf16(a_h, b_l0, acc0, 0, 0, 0);
            acc1 = __builtin_amdgcn_mfma_f32_16x16x32_bf16(a_h, b_l1, acc1, 0, 0, 0);
            acc0 = __builtin_amdgcn_mfma_f32_16x16x32_bf16(a_l, b_h0, acc0, 0, 0, 0);
            acc1 = __builtin_amdgcn_mfma_f32_16x16x32_bf16(a_l, b_h1, acc1, 0, 0, 0);
        }
        if (ks < 15) { WRITES(cur ^ 1); __syncthreads(); cur ^= 1; }
    }

    // epilogue: D row = (lane>>4)*4 + r, col = lane&15  (m89-verified layout)
    const int s_base = row0 + wm * 16 + (lane >> 4) * 4;
    const int cc0 = col0 + bc0, cc1 = col0 + bc1;
#pragma unroll
    for (int r = 0; r < 4; ++r) {
        const int s   = s_base + r;
        const int dir = s >> 9;
        const int c   = s & 511;
        const int t   = c * CHUNK + (i - WU);
        float h0, h1;
        if (t < 0) {
            h0 = 0.f; h1 = 0.f;                   // exact masked warm-up
        } else {
            const int xrow = dir ? (SEQ - 1 - t) : t;
            h0 = tanhf(acc0[r] + xp[(size_t)xrow * DIM + cc0]);
            h1 = tanhf(acc1[r] + xp[(size_t)xrow * DIM + cc1]);
        }
        const unsigned short h0h = f2bf(h0);
        const unsigned short h0l = f2bf(h0 - bf2f(h0h));
        const unsigned short h1h = f2bf(h1);
        const unsigned short h1l = f2bf(h1 - bf2f(h1h));
        Hhi_out[(size_t)s * DIM + cc0] = h0h; Hlo_out[(size_t)s * DIM + cc0] = h0l;
        Hhi_out[(size_t)s * DIM + cc1] = h1h; Hlo_out[(size_t)s * DIM + cc1] = h1l;
        if (i >= WU) {
            const int orow = dir ? (SEQ + t) : t;
            out[(size_t)orow * DIM + cc0] = h0;
            out[(size_t)orow * DIM + cc1] = h1;
        }
    }
}

// ---------------------------------------------------------------------------
extern "C" void kernel_launch(void* const* d_in, const int* in_sizes, int n_in,
                              void* d_out, int out_size, void* d_ws, size_t ws_size,
                              hipStream_t stream)
{
    (void)in_sizes; (void)n_in; (void)out_size; (void)ws_size;
    const float* x  = (const float*)d_in[0];
    const float* Wx = (const float*)d_in[1];
    const float* Wh = (const float*)d_in[2];
    const float* b  = (const float*)d_in[3];
    float* out = (float*)d_out;

    char* ws = (char*)d_ws;
    const size_t MB = 1ull << 20;
    float*          xp   = (float*)ws;                       // [0, 64MB)
    unsigned short* Hbuf = (unsigned short*)(ws + 64 * MB);  // 4 x 2MB
    unsigned short* Hhi[2] = {Hbuf,            Hbuf + 2 * (1 << 20)};
    unsigned short* Hlo[2] = {Hbuf + (1 << 20), Hbuf + 3 * (1 << 20)};
    unsigned short* WhTh = (unsigned short*)(ws + 72 * MB);  // [72, 74MB)
    unsigned short* WhTl = WhTh + (1 << 20);                 // [74, 76MB)

    hipLaunchKernelGGL(whsplit_kernel, dim3(256), dim3(256), 0, stream, Wh, WhTh, WhTl);
    hipLaunchKernelGGL(xproj_kernel, dim3(4096), dim3(256), 0, stream, x, Wx, b, xp);
    hipMemsetAsync(Hbuf, 0, 4 * MB, stream);                 // Hhi[0] + Hlo[0] = 0

    int p = 0;
    for (int i = 0; i < NSTEP; ++i) {
        hipLaunchKernelGGL(step_mfma, dim3(512), dim3(256), 0, stream,
                           Hhi[p], Hlo[p], Hhi[p ^ 1], Hlo[p ^ 1],
                           xp, WhTh, WhTl, out, i);
        p ^= 1;
    }
}

// Round 3
// 1466.609 us; speedup vs baseline: 23.0934x; 1.9688x over previous
//
#include <hip/hip_runtime.h>
#include <math.h>

#define SEQ   16384
#define DIM   1024
#define WU    32                    // warm-up steps (32 empirically proven: chunk-1 in r1/r2)
#define CHUNK 32
#define NCH   (SEQ / CHUNK)         // 512 chunks per direction
#define NSTR  (2 * NCH)             // 1024 parallel streams
#define NSTEP (WU + CHUNK)          // 64 batched steps

typedef __attribute__((ext_vector_type(8)))  short bf16x8;
typedef __attribute__((ext_vector_type(16))) float f32x16;

__device__ __forceinline__ unsigned short f2bf(float f) {
    unsigned int x = __float_as_uint(f);
    unsigned int r = (x + 0x7fffu + ((x >> 16) & 1u)) >> 16;
    return (unsigned short)r;
}
__device__ __forceinline__ float bf2f(unsigned short u) {
    return __uint_as_float(((unsigned int)u) << 16);
}

// ---------------------------------------------------------------------------
// W (KxN fp32, k-major) -> n-major NxK bf16 hi/lo pair. Used for Wx and Wh.
// ---------------------------------------------------------------------------
__global__ __launch_bounds__(256)
void wsplit_kernel(const float* __restrict__ W,
                   unsigned short* __restrict__ WTh,
                   unsigned short* __restrict__ WTl)
{
    const int bk = blockIdx.x & 15, bn = blockIdx.x >> 4;
    const int k0 = bk * 64, n0 = bn * 64;
    const int tid = threadIdx.x;
    __shared__ float T[64][65];
#pragma unroll
    for (int it = 0; it < 4; ++it) {
        int f = tid + 256 * it;
        int r = f >> 4;
        int c4 = (f & 15) << 2;
        const float4 v = *reinterpret_cast<const float4*>(
            &W[(size_t)(k0 + r) * DIM + n0 + c4]);
        T[r][c4 + 0] = v.x; T[r][c4 + 1] = v.y;
        T[r][c4 + 2] = v.z; T[r][c4 + 3] = v.w;
    }
    __syncthreads();
#pragma unroll
    for (int it = 0; it < 4; ++it) {
        int f  = tid + 256 * it;
        int rn = f >> 4;
        int c4 = (f & 15) << 2;
        float vv[4] = {T[c4 + 0][rn], T[c4 + 1][rn], T[c4 + 2][rn], T[c4 + 3][rn]};
        ushort4 hi, lo;
        unsigned short h[4], l[4];
#pragma unroll
        for (int j = 0; j < 4; ++j) {
            h[j] = f2bf(vv[j]);
            l[j] = f2bf(vv[j] - bf2f(h[j]));
        }
        hi.x = h[0]; hi.y = h[1]; hi.z = h[2]; hi.w = h[3];
        lo.x = l[0]; lo.y = l[1]; lo.z = l[2]; lo.w = l[3];
        *reinterpret_cast<ushort4*>(&WTh[(size_t)(n0 + rn) * DIM + k0 + c4]) = hi;
        *reinterpret_cast<ushort4*>(&WTl[(size_t)(n0 + rn) * DIM + k0 + c4]) = lo;
    }
}

// ---------------------------------------------------------------------------
// x (fp32, row-major) -> xh/xl bf16 hi/lo, same layout. Memory-bound.
// ---------------------------------------------------------------------------
__global__ __launch_bounds__(256)
void xsplit_kernel(const float* __restrict__ x,
                   unsigned short* __restrict__ xh,
                   unsigned short* __restrict__ xl)
{
    const int N4 = SEQ * DIM / 4;
    for (int idx = blockIdx.x * 256 + threadIdx.x; idx < N4; idx += gridDim.x * 256) {
        const float4 v = reinterpret_cast<const float4*>(x)[idx];
        ushort4 h, l;
        h.x = f2bf(v.x); l.x = f2bf(v.x - bf2f(h.x));
        h.y = f2bf(v.y); l.y = f2bf(v.y - bf2f(h.y));
        h.z = f2bf(v.z); l.z = f2bf(v.z - bf2f(h.z));
        h.w = f2bf(v.w); l.w = f2bf(v.w - bf2f(h.w));
        reinterpret_cast<ushort4*>(xh)[idx] = h;
        reinterpret_cast<ushort4*>(xl)[idx] = l;
    }
}

// ---------------------------------------------------------------------------
// xproj = x @ Wx + b via MFMA 32x32x16, 3-term hi/lo split (fp32-accurate).
// Block 128x128, 4 waves 2x2 (wave 64x64 = 2x2 acc tiles), BK=32,
// single-buffered LDS + register prefetch. Grid 1024 (bn = XCD-stationary).
// LDS rows [.][40] shorts (80B): base bank 20r mod 32 -> rows 0..7 cover all
// 32 banks; 32-lane 16B frag reads are bank-uniform (4 accesses/bank = min).
// ---------------------------------------------------------------------------
__global__ __launch_bounds__(256)
void xproj_mfma(const unsigned short* __restrict__ xh,
                const unsigned short* __restrict__ xl,
                const unsigned short* __restrict__ WxTh,
                const unsigned short* __restrict__ WxTl,
                const float* __restrict__ b, float* __restrict__ xp)
{
    const int bn = blockIdx.x & 7, bm = blockIdx.x >> 3;
    const int row0 = bm * 128, col0 = bn * 128;
    const int tid = threadIdx.x, lane = tid & 63, w = tid >> 6;
    const int wm = w >> 1, wn = w & 1;

    __shared__ unsigned short Ah[128][40], Al[128][40], Bh[128][40], Bl[128][40];

    f32x16 acc[2][2];
#pragma unroll
    for (int mi = 0; mi < 2; ++mi)
#pragma unroll
        for (int ni = 0; ni < 2; ++ni)
#pragma unroll
            for (int r = 0; r < 16; ++r) acc[mi][ni][r] = 0.f;

    const int sr = tid >> 1;              // staging row 0..127
    const int sk = (tid & 1) * 16;        // k chunk base (16 bf16 = 2 uint4)
    const size_t ga = (size_t)(row0 + sr) * DIM + sk;
    const size_t gb = (size_t)(col0 + sr) * DIM + sk;

    uint4 pah[2], pal[2], pbh[2], pbl[2];

#define XLOAD(k0_) do {                                                        \
        pah[0] = *reinterpret_cast<const uint4*>(xh   + ga + (k0_));           \
        pah[1] = *reinterpret_cast<const uint4*>(xh   + ga + (k0_) + 8);       \
        pal[0] = *reinterpret_cast<const uint4*>(xl   + ga + (k0_));           \
        pal[1] = *reinterpret_cast<const uint4*>(xl   + ga + (k0_) + 8);       \
        pbh[0] = *reinterpret_cast<const uint4*>(WxTh + gb + (k0_));           \
        pbh[1] = *reinterpret_cast<const uint4*>(WxTh + gb + (k0_) + 8);       \
        pbl[0] = *reinterpret_cast<const uint4*>(WxTl + gb + (k0_));           \
        pbl[1] = *reinterpret_cast<const uint4*>(WxTl + gb + (k0_) + 8);       \
    } while (0)

    XLOAD(0);
    const int am0 = wm * 64 + (lane & 31), am1 = am0 + 32;
    const int bn0 = wn * 64 + (lane & 31), bn1 = bn0 + 32;
    const int kh  = (lane >> 5) * 8;

    for (int kt = 0; kt < 32; ++kt) {
        __syncthreads();                              // prev reads done
        *reinterpret_cast<uint4*>(&Ah[sr][sk])     = pah[0];
        *reinterpret_cast<uint4*>(&Ah[sr][sk + 8]) = pah[1];
        *reinterpret_cast<uint4*>(&Al[sr][sk])     = pal[0];
        *reinterpret_cast<uint4*>(&Al[sr][sk + 8]) = pal[1];
        *reinterpret_cast<uint4*>(&Bh[sr][sk])     = pbh[0];
        *reinterpret_cast<uint4*>(&Bh[sr][sk + 8]) = pbh[1];
        *reinterpret_cast<uint4*>(&Bl[sr][sk])     = pbl[0];
        *reinterpret_cast<uint4*>(&Bl[sr][sk + 8]) = pbl[1];
        __syncthreads();
        if (kt < 31) XLOAD((size_t)(kt + 1) * 32);    // prefetch under compute
#pragma unroll
        for (int ks = 0; ks < 2; ++ks) {
            const int ko = ks * 16 + kh;
            bf16x8 a0h = *reinterpret_cast<const bf16x8*>(&Ah[am0][ko]);
            bf16x8 a1h = *reinterpret_cast<const bf16x8*>(&Ah[am1][ko]);
            bf16x8 a0l = *reinterpret_cast<const bf16x8*>(&Al[am0][ko]);
            bf16x8 a1l = *reinterpret_cast<const bf16x8*>(&Al[am1][ko]);
            bf16x8 b0h = *reinterpret_cast<const bf16x8*>(&Bh[bn0][ko]);
            bf16x8 b1h = *reinterpret_cast<const bf16x8*>(&Bh[bn1][ko]);
            bf16x8 b0l = *reinterpret_cast<const bf16x8*>(&Bl[bn0][ko]);
            bf16x8 b1l = *reinterpret_cast<const bf16x8*>(&Bl[bn1][ko]);
            acc[0][0] = __builtin_amdgcn_mfma_f32_32x32x16_bf16(a0h, b0h, acc[0][0], 0, 0, 0);
            acc[0][1] = __builtin_amdgcn_mfma_f32_32x32x16_bf16(a0h, b1h, acc[0][1], 0, 0, 0);
            acc[1][0] = __builtin_amdgcn_mfma_f32_32x32x16_bf16(a1h, b0h, acc[1][0], 0, 0, 0);
            acc[1][1] = __builtin_amdgcn_mfma_f32_32x32x16_bf16(a1h, b1h, acc[1][1], 0, 0, 0);
            acc[0][0] = __builtin_amdgcn_mfma_f32_32x32x16_bf16(a0h, b0l, acc[0][0], 0, 0, 0);
            acc[0][1] = __builtin_amdgcn_mfma_f32_32x32x16_bf16(a0h, b1l, acc[0][1], 0, 0, 0);
            acc[1][0] = __builtin_amdgcn_mfma_f32_32x32x16_bf16(a1h, b0l, acc[1][0], 0, 0, 0);
            acc[1][1] = __builtin_amdgcn_mfma_f32_32x32x16_bf16(a1h, b1l, acc[1][1], 0, 0, 0);
            acc[0][0] = __builtin_amdgcn_mfma_f32_32x32x16_bf16(a0l, b0h, acc[0][0], 0, 0, 0);
            acc[0][1] = __builtin_amdgcn_mfma_f32_32x32x16_bf16(a0l, b1h, acc[0][1], 0, 0, 0);
            acc[1][0] = __builtin_amdgcn_mfma_f32_32x32x16_bf16(a1l, b0h, acc[1][0], 0, 0, 0);
            acc[1][1] = __builtin_amdgcn_mfma_f32_32x32x16_bf16(a1l, b1h, acc[1][1], 0, 0, 0);
        }
    }
#undef XLOAD

    // C layout (m74/m101): col = lane&31, row = (r&3) + 8*(r>>2) + 4*(lane>>5)
    const int rbase = 4 * (lane >> 5);
#pragma unroll
    for (int mi = 0; mi < 2; ++mi) {
#pragma unroll
        for (int ni = 0; ni < 2; ++ni) {
            const int col = col0 + wn * 64 + ni * 32 + (lane & 31);
            const float bb = b[col];
#pragma unroll
            for (int r = 0; r < 16; ++r) {
                const int row = row0 + wm * 64 + mi * 32 + (r & 3) + 8 * (r >> 2) + rbase;
                xp[(size_t)row * DIM + col] = acc[mi][ni][r] + bb;
            }
        }
    }
}

// ---------------------------------------------------------------------------
// One batched recurrence step, MFMA 32x32x16, 2-term (H bf16, Wh hi/lo):
//   S = H*Wh_hi + H*Wh_lo;  h = tanh(S + xp[row(s)])
// Block 64x64, 512 thr = 8 waves: groups g=0/1 split K (each 512), waves
// within group 2x2 of 32x32 tiles; LDS reduce combines the K halves.
// Single-buffered LDS + reg prefetch; grid 256 (XCD-stationary Wh panels).
// ---------------------------------------------------------------------------
__global__ __launch_bounds__(512)
void step32(const unsigned short* __restrict__ Hin,
            unsigned short* __restrict__ Hout,
            const float* __restrict__ xp,
            const unsigned short* __restrict__ WhTh,
            const unsigned short* __restrict__ WhTl,
            float* __restrict__ out, const int i)
{
    const int bid = ((blockIdx.x & 7) << 5) | (blockIdx.x >> 3);  // XCD swizzle
    const int bm = bid & 15, bn = bid >> 4;
    const int row0 = bm * 64, col0 = bn * 64;
    const int tid = threadIdx.x, lane = tid & 63, w = tid >> 6;
    const int g = w >> 2, wi = w & 3, wm = wi >> 1, wn = wi & 1;

    __shared__ unsigned short A[2][64][72];    // [kgroup][row][k]
    __shared__ unsigned short Bh[2][64][72];
    __shared__ unsigned short Bl[2][64][72];   // aliased as Red after k-loop

    f32x16 acc;
#pragma unroll
    for (int r = 0; r < 16; ++r) acc[r] = 0.f;

    const int sr = tid >> 3;                   // 0..63
    const int sc = (tid & 7) * 8;              // k chunk (8 bf16 = 16B)
    const size_t gA = (size_t)(row0 + sr) * DIM + sc;
    const size_t gB = (size_t)(col0 + sr) * DIM + sc;

    uint4 pa0, pa1, pbh0, pbh1, pbl0, pbl1;

#define SLOAD(it_) do {                                                          \
        const size_t k0_ = (size_t)(it_) * 64, k1_ = (size_t)((it_) + 8) * 64;   \
        pa0  = *reinterpret_cast<const uint4*>(Hin  + gA + k0_);                 \
        pa1  = *reinterpret_cast<const uint4*>(Hin  + gA + k1_);                 \
        pbh0 = *reinterpret_cast<const uint4*>(WhTh + gB + k0_);                 \
        pbh1 = *reinterpret_cast<const uint4*>(WhTh + gB + k1_);                 \
        pbl0 = *reinterpret_cast<const uint4*>(WhTl + gB + k0_);                 \
        pbl1 = *reinterpret_cast<const uint4*>(WhTl + gB + k1_);                 \
    } while (0)

    SLOAD(0);
    const int ar = wm * 32 + (lane & 31);
    const int br = wn * 32 + (lane & 31);
    const int kh = (lane >> 5) * 8;

    for (int it = 0; it < 8; ++it) {
        __syncthreads();                       // prev reads done
        *reinterpret_cast<uint4*>(&A[0][sr][sc])  = pa0;
        *reinterpret_cast<uint4*>(&A[1][sr][sc])  = pa1;
        *reinterpret_cast<uint4*>(&Bh[0][sr][sc]) = pbh0;
        *reinterpret_cast<uint4*>(&Bh[1][sr][sc]) = pbh1;
        *reinterpret_cast<uint4*>(&Bl[0][sr][sc]) = pbl0;
        *reinterpret_cast<uint4*>(&Bl[1][sr][sc]) = pbl1;
        __syncthreads();
        if (it < 7) SLOAD(it + 1);             // prefetch under compute
#pragma unroll
        for (int ks = 0; ks < 4; ++ks) {
            const int ko = ks * 16 + kh;
            bf16x8 a  = *reinterpret_cast<const bf16x8*>(&A[g][ar][ko]);
            bf16x8 bh = *reinterpret_cast<const bf16x8*>(&Bh[g][br][ko]);
            bf16x8 bl = *reinterpret_cast<const bf16x8*>(&Bl[g][br][ko]);
            acc = __builtin_amdgcn_mfma_f32_32x32x16_bf16(a, bh, acc, 0, 0, 0);
            acc = __builtin_amdgcn_mfma_f32_32x32x16_bf16(a, bl, acc, 0, 0, 0);
        }
    }
#undef SLOAD

    // combine K halves: group1 -> LDS (alias Bl), group0 adds + epilogue
    __syncthreads();
    float* Red = reinterpret_cast<float*>(&Bl[0][0][0]);   // 16KB <= 18.4KB
    if (g == 1) {
#pragma unroll
        for (int r = 0; r < 16; ++r) Red[(wi * 16 + r) * 64 + lane] = acc[r];
    }
    __syncthreads();
    if (g == 0) {
        const int col = col0 + wn * 32 + (lane & 31);
        const int rbase = 4 * (lane >> 5);
#pragma unroll
        for (int r = 0; r < 16; ++r) {
            const float v = acc[r] + Red[(wi * 16 + r) * 64 + lane];
            const int srow = (r & 3) + 8 * (r >> 2) + rbase;
            const int s = row0 + wm * 32 + srow;
            const int dir = s >> 9;
            const int c   = s & 511;
            const int t   = c * CHUNK + (i - WU);
            float h = 0.f;
            if (t >= 0) {
                const int xrow = dir ? (SEQ - 1 - t) : t;
                h = tanhf(v + xp[(size_t)xrow * DIM + col]);
            }
            Hout[(size_t)s * DIM + col] = f2bf(h);
            if (i >= WU) {                       // t >= 0 guaranteed
                const int orow = dir ? (SEQ + t) : t;
                out[(size_t)orow * DIM + col] = h;
            }
        }
    }
}

// ---------------------------------------------------------------------------
extern "C" void kernel_launch(void* const* d_in, const int* in_sizes, int n_in,
                              void* d_out, int out_size, void* d_ws, size_t ws_size,
                              hipStream_t stream)
{
    (void)in_sizes; (void)n_in; (void)out_size; (void)ws_size;
    const float* x  = (const float*)d_in[0];
    const float* Wx = (const float*)d_in[1];
    const float* Wh = (const float*)d_in[2];
    const float* b  = (const float*)d_in[3];
    float* out = (float*)d_out;

    char* ws = (char*)d_ws;
    const size_t MB = 1ull << 20;
    float*          xp   = (float*)ws;                        // [0, 64MB)
    unsigned short* WxTh = (unsigned short*)(ws + 64 * MB);   // 2MB each
    unsigned short* WxTl = (unsigned short*)(ws + 66 * MB);
    unsigned short* WhTh = (unsigned short*)(ws + 68 * MB);
    unsigned short* WhTl = (unsigned short*)(ws + 70 * MB);
    unsigned short* H0   = (unsigned short*)(ws + 72 * MB);
    unsigned short* H1   = (unsigned short*)(ws + 74 * MB);   // end 76MB

    // x hi/lo lives in d_out's first 64MB; steps (i>=WU) overwrite it later.
    unsigned short* xh = (unsigned short*)d_out;
    unsigned short* xl = xh + (size_t)SEQ * DIM;

    hipLaunchKernelGGL(wsplit_kernel, dim3(256), dim3(256), 0, stream, Wx, WxTh, WxTl);
    hipLaunchKernelGGL(wsplit_kernel, dim3(256), dim3(256), 0, stream, Wh, WhTh, WhTl);
    hipLaunchKernelGGL(xsplit_kernel, dim3(2048), dim3(256), 0, stream, x, xh, xl);
    hipLaunchKernelGGL(xproj_mfma, dim3(1024), dim3(256), 0, stream,
                       xh, xl, WxTh, WxTl, b, xp);
    hipMemsetAsync(H0, 0, 2 * MB, stream);

    unsigned short* cur = H0;
    unsigned short* nxt = H1;
    for (int i = 0; i < NSTEP; ++i) {
        hipLaunchKernelGGL(step32, dim3(256), dim3(512), 0, stream,
                           cur, nxt, xp, WhTh, WhTl, out, i);
        unsigned short* tmp = cur; cur = nxt; nxt = tmp;
    }
}